// Round 15
// baseline (528.238 us; speedup 1.0000x reference)
//
#include <hip/hip_runtime.h>
#include <hip/hip_bf16.h>

// MPS chain: y[b,c] over 784 sites, chi=64, d=2, 10 ch, batch 1024.
// R15 = R14 m-split with the saddr fix: sbase stays BLOCK-UNIFORM (SGPR);
// the wave's half-offset lives in the VGPR voffset (w*8192 bytes).
// Design: each chain (ch, 16-col tile) run by TWO waves; wave w owns output
// slots [32w,32w+32) with slot(w,mt,mu)=32w+8*(mu>>2)+4*mt+(mu&3), so lane
// (g,l15) D rows {4g+r, tile mt} = phys bonds {32w+8g+4mt+r} = EXACTLY its
// tf_self[j=4mt+r] (kf=w half lane-local); tf_other = same lane of other
// wave -> exchange is ONE ds_write_b128 + ONE ds_read_b128 per site,
// double-buffered, "lgkmcnt(0); s_barrier" (vm prefetches stay in flight).
// Slot<->phys bond is IDENTITY at the B-operand (verified algebra, same
// mechanism as R6-R13), so masked-wsA physics is unchanged.
// Per wave per site: 8 asm global_load_dwordx4 (dist-2, 4 bufs, WAIT8),
// 8 MFMA (self-kf first, overlapping the ds_read), slim epilogue.
// vmcnt ledger: prologue {2x,8 B0,8 B1}=18, WAIT8 -> x+B0 done, B1 in
// flight. body(n): +8 (site n+2) ->16; WAIT8 drains site n+1. Group-top
// x (+2) drained by body0's WAIT8 before next-group use.
// Layouts (verified R1-R13): A-op m=l&15, k=8*(l>>4)+j; B-op col=l&15,
// same k; D row=4*(l>>4)+r, col=l&15.

#define LEN 784
#define NCH 10

typedef short bf16x8 __attribute__((ext_vector_type(8)));
typedef float f32x4  __attribute__((ext_vector_type(4)));
typedef unsigned int u32x4 __attribute__((ext_vector_type(4)));

#define WSA_SHORTS ((size_t)NCH * LEN * 8192)
#define WSX_FLOATS ((size_t)1024 * 2 * LEN)
#define WS_NEED (WSA_SHORTS * 2 + WSX_FLOATS * 4)

#define XSCALE -2.88539008177792681f   // -2*log2(e)
#define XUNDO  -0.34657359027997264f   // 1/XSCALE

static __device__ __forceinline__ unsigned short f2bf(float f) {
    union { __hip_bfloat16 h; unsigned short s; } u;
    u.h = __float2bfloat16(f);
    return u.s;
}

static __device__ __forceinline__ unsigned pack_bf2(float a, float b) {
    union { __hip_bfloat162 h; unsigned u; } c;
    c.h = __float22bfloat162_rn(float2{a, b});
    return c.u;
}

static __device__ __forceinline__ int site_dlim(int m) {
    int e1 = m < 6 ? (1 << m) : 64;
    int e2 = (LEN - m) < 6 ? (1 << (LEN - m)) : 64;
    return e1 < e2 ? e1 : e2;
}

// ---- pre-pass: tensors -> bf16 frag-order wsA for the m-split layout,
//      x -> wsX[b][2n+i] pre-scaled by -2*log2(e) ----
// thread t = [w:1][mt:1][ii:1][kfp:1][lane:6]; kf = kfp ^ w (self-kf first).
// frag value j: a_in = 32*kf + 8g + j (physical, masked),
// bout = slot(w,mt,l15) = 32w + 8*(l15>>2) + 4*mt + (l15&3).
__global__ __launch_bounds__(1024) void prepass(const float* __restrict__ x,
                                                const float* __restrict__ tens,
                                                short* __restrict__ wsA,
                                                float* __restrict__ wsX)
{
    const int bid = blockIdx.x;
    const int t = threadIdx.x;
    if (bid < NCH * LEN) {
        const int site = bid % LEN;
        const int dlim = site_dlim(site);
        const int w = t >> 9, mt = (t >> 8) & 1, ii = (t >> 7) & 1,
                  kfp = (t >> 6) & 1, l = t & 63;
        const int g = l >> 4, l15 = l & 15;
        const int kf = kfp ^ w;
        const int bout = 32 * w + 8 * (l15 >> 2) + 4 * mt + (l15 & 3);
        const int a0 = 32 * kf + 8 * g;
        const float* src = tens + (size_t)bid * 8192;   // [a][i][bout]
        unsigned int wv[4];
        #pragma unroll
        for (int p = 0; p < 4; ++p) {
            int aA = a0 + 2 * p, aB = a0 + 2 * p + 1;
            float f0 = (aA < dlim) ? src[(size_t)aA * 128 + ii * 64 + bout] : 0.f;
            float f1 = (aB < dlim) ? src[(size_t)aB * 128 + ii * 64 + bout] : 0.f;
            wv[p] = (unsigned)f2bf(f0) | ((unsigned)f2bf(f1) << 16);
        }
        *(int4*)(wsA + (size_t)bid * 8192 + (size_t)t * 8) = *(int4*)wv;
    } else {
        int b = bid - NCH * LEN;
        if (t < LEN) {
            float v0 = x[(size_t)b * (2 * LEN) + t] * XSCALE;
            float v1 = x[(size_t)b * (2 * LEN) + LEN + t] * XSCALE;
            float2 pk; pk.x = v0; pk.y = v1;
            *(float2*)(wsX + (size_t)b * (2 * LEN) + 2 * t) = pk;
        }
    }
}

// one global_load_dwordx4: dst <- mem[sbase(SGPR) + voff(VGPR) + imm]
#define GLOAD(dst, voffr, sbase, imm) \
    asm volatile("global_load_dwordx4 %0, %1, %2 offset:" #imm \
                 : "=v"(dst) : "v"(voffr), "s"(sbase))

#define WAIT8() do { \
    asm volatile("s_waitcnt vmcnt(8)" ::: "memory"); \
    __builtin_amdgcn_sched_barrier(0); \
} while (0)

// LDS-visibility fence + barrier; vm loads stay in flight
#define BARX() asm volatile("s_waitcnt lgkmcnt(0)\n\ts_barrier" ::: "memory")

// ---- main chain kernel: 2 waves per chain (m-split), 128 threads ----
__global__ __launch_bounds__(128) void mps_fwd15(const short* __restrict__ wsA,
                                                 const float* __restrict__ wsX,
                                                 float* __restrict__ out)
{
    __shared__ short ex[2][2][512];   // [buf][wave][lane*8] exchange halves

    const int tid = threadIdx.x;
    const int lane = tid & 63;
    const int w = tid >> 6;           // wave 0/1 = slot half
    const int g = lane >> 4, l15 = lane & 15;

    // XCD-aware: 640 = 8 XCDs x 80 chains; each XCD sees <=2 channels
    const int p = blockIdx.x;
    const int gidx = (p & 7) * 80 + (p >> 3);
    const int ch = gidx >> 6;
    const int b0 = (gidx & 63) * 16;

    const short* asrc = wsA + (size_t)ch * LEN * 8192;   // block-uniform (SGPR)
    const float* xsrc = wsX + (size_t)(b0 + l15) * (2 * LEN);

    // wave half offset folded into the VGPR voffset (bytes):
    // frag f at w*8192 + f*1024 + lane*16
    const int voff0 = w * 8192 + lane * 16;   // frags 0..3 via imm 0..3072
    const int voff1 = voff0 + 4096;           // frags 4..7

    const f32x4 Z = (f32x4){0.f, 0.f, 0.f, 0.f};

    // t-state: tf_self = own kf(=w) half, phys bonds 32w+8g+j
    bf16x8 tf_self;
    #pragma unroll
    for (int j = 0; j < 8; ++j) tf_self[j] = 0;
    if (w == 0 && g == 0) tf_self[0] = (short)0x3F80;   // phys a=0

    auto loadA = [&](int site, u32x4 (&A)[8]) {
        site = site < LEN ? site : LEN - 1;
        const short* sb = asrc + (size_t)site * 8192;    // uniform -> SGPR
        GLOAD(A[0], voff0, sb, 0);    GLOAD(A[1], voff0, sb, 1024);
        GLOAD(A[2], voff0, sb, 2048); GLOAD(A[3], voff0, sb, 3072);
        GLOAD(A[4], voff1, sb, 0);    GLOAD(A[5], voff1, sb, 1024);
        GLOAD(A[6], voff1, sb, 2048); GLOAD(A[7], voff1, sb, 3072);
    };

    auto loadX = [&](int nb, float4& qa, float4& qb) {
        nb = nb <= LEN - 4 ? nb : LEN - 4;
        const float* sx = xsrc + 2 * nb;
        asm volatile("global_load_dwordx4 %0, %1, off"
                     : "=v"(qa) : "v"(sx));
        asm volatile("global_load_dwordx4 %0, %1, off offset:16"
                     : "=v"(qb) : "v"(sx));
    };

    auto body = [&](int n, u32x4 (&Ac)[8], u32x4 (&Al)[8],
                    float x0s, float x1s) {
        // (1) distance-2 prefetch (site n+2)
        loadA(n + 2, Al);
        __builtin_amdgcn_sched_barrier(0);

        // (2) other-half t for THIS site (written by other wave last body;
        //     last body's barrier made it visible)
        bf16x8 tfo = *(const bf16x8*)&ex[n & 1][1 - w][lane * 8];

        // (3) 8 MFMA: self-kf first (reg-resident), then other-kf
        f32x4 acc[2][2];    // [mt][ii]
        __builtin_amdgcn_s_setprio(1);
        #pragma unroll
        for (int mt = 0; mt < 2; ++mt)
            #pragma unroll
            for (int ii = 0; ii < 2; ++ii)
                acc[mt][ii] = __builtin_amdgcn_mfma_f32_16x16x32_bf16(
                    __builtin_bit_cast(bf16x8, Ac[mt * 4 + ii * 2 + 0]),
                    tf_self, Z, 0, 0, 0);
        #pragma unroll
        for (int mt = 0; mt < 2; ++mt)
            #pragma unroll
            for (int ii = 0; ii < 2; ++ii)
                acc[mt][ii] = __builtin_amdgcn_mfma_f32_16x16x32_bf16(
                    __builtin_bit_cast(bf16x8, Ac[mt * 4 + ii * 2 + 1]),
                    tfo, acc[mt][ii], 0, 0, 0);
        __builtin_amdgcn_s_setprio(0);

        // (4) epilogue: combine + sigmoid -> own next-half; exchange write
        if (n == LEN - 1) {
            // phys bond 0 = (w=0, mt=0, g=0, r=0); no activation; undo scale
            if (w == 0 && g == 0) {
                float v = (x0s * acc[0][0][0] + x1s * acc[0][1][0]) * XUNDO;
                out[(size_t)(b0 + l15) * NCH + ch] = v;
            }
        } else {
            unsigned pk[4];   // j = 4mt + r
            #pragma unroll
            for (int mt = 0; mt < 2; ++mt) {
                float s[4];
                #pragma unroll
                for (int r = 0; r < 4; ++r) {
                    float u = x0s * acc[mt][0][r] + x1s * acc[mt][1][r];
                    float exv = __builtin_amdgcn_exp2f(u);
                    s[r] = __builtin_amdgcn_rcpf(1.0f + exv);
                }
                pk[mt * 2 + 0] = pack_bf2(s[0], s[1]);
                pk[mt * 2 + 1] = pack_bf2(s[2], s[3]);
            }
            union { unsigned u[4]; bf16x8 v; } nf;
            nf.u[0] = pk[0]; nf.u[1] = pk[1]; nf.u[2] = pk[2]; nf.u[3] = pk[3];
            tf_self = nf.v;
            *(bf16x8*)&ex[(n + 1) & 1][w][lane * 8] = nf.v;   // for other wave
        }

        // (5) counted vm wait (site n+1 staged) + LDS fence + barrier
        WAIT8();
        BARX();
    };

    u32x4 B0[8], B1[8], B2[8], B3[8];
    float4 xa, xb, xna, xnb;

    // prologue: seed exchange buf0; stage sites 0,1
    *(bf16x8*)&ex[0][w][lane * 8] = tf_self;
    loadX(0, xa, xb);       // 2
    loadA(0, B0);           // 8
    loadA(1, B1);           // 8  -> 18 outstanding
    WAIT8();                // x + B0 ready; B1 in flight
    BARX();                 // init exchange visible

    for (int nb = 0; nb < LEN; nb += 4) {
        loadX(nb + 4, xna, xnb);                  // drained by body0's WAIT8
        body(nb + 0, B0, B2, xa.x, xa.y);
        body(nb + 1, B1, B3, xa.z, xa.w);
        body(nb + 2, B2, B0, xb.x, xb.y);
        body(nb + 3, B3, B1, xb.z, xb.w);
        xa = xna; xb = xnb;
    }
}

// ---- fallback (ws too small): R13 plain path on raw inputs ----
__global__ __launch_bounds__(64) void mps_fwd15_fb(const float* __restrict__ x,
                                                   const float* __restrict__ tens,
                                                   float* __restrict__ out)
{
    const int lane = threadIdx.x;
    const int g = lane >> 4, l15 = lane & 15;
    const int p = blockIdx.x;
    const int gidx = (p & 7) * 80 + (p >> 3);
    const int ch = gidx >> 6;
    const int b0 = (gidx & 63) * 16;

    const float* tsrc = tens + (size_t)ch * LEN * 8192;
    const float* xsrc = x + (size_t)(b0 + l15) * (2 * LEN);

    bf16x8 tf0, tf1;
    #pragma unroll
    for (int j = 0; j < 8; ++j) { tf0[j] = 0; tf1[j] = 0; }
    if (g == 0) tf0[0] = (short)0x3F80;

    for (int n = 0; n < LEN; ++n) {
        const int dlim = site_dlim(n);
        const float* sb = tsrc + (size_t)n * 8192;
        bf16x8 A[16];
        #pragma unroll
        for (int f = 0; f < 16; ++f) {
            int mt = f >> 2, ii = (f >> 1) & 1, kf = f & 1;
            int bout = 32 * (mt >> 1) + 8 * (l15 >> 2) + 4 * (mt & 1) + (l15 & 3);
            int a0 = 32 * kf + 8 * g;
            unsigned int wv[4];
            #pragma unroll
            for (int q2 = 0; q2 < 4; ++q2) {
                int aA = a0 + 2 * q2, aB = aA + 1;
                float f0 = (aA < dlim) ? sb[(size_t)aA * 128 + ii * 64 + bout] : 0.f;
                float f1 = (aB < dlim) ? sb[(size_t)aB * 128 + ii * 64 + bout] : 0.f;
                wv[q2] = (unsigned)f2bf(f0) | ((unsigned)f2bf(f1) << 16);
            }
            A[f] = *(bf16x8*)wv;
        }
        float x0s = xsrc[n] * XSCALE, x1s = xsrc[LEN + n] * XSCALE;

        f32x4 acc[4][2];
        #pragma unroll
        for (int mt = 0; mt < 4; ++mt)
            #pragma unroll
            for (int ii = 0; ii < 2; ++ii)
                acc[mt][ii] = (f32x4){0.f, 0.f, 0.f, 0.f};
        #pragma unroll
        for (int kf = 0; kf < 2; ++kf) {
            bf16x8 tfk = kf ? tf1 : tf0;
            #pragma unroll
            for (int mt = 0; mt < 4; ++mt)
                #pragma unroll
                for (int ii = 0; ii < 2; ++ii)
                    acc[mt][ii] = __builtin_amdgcn_mfma_f32_16x16x32_bf16(
                        A[mt * 4 + ii * 2 + kf], tfk, acc[mt][ii], 0, 0, 0);
        }

        if (n == LEN - 1) {
            if (g == 0) {
                float v = (x0s * acc[0][0][0] + x1s * acc[0][1][0]) * XUNDO;
                out[(size_t)(b0 + l15) * NCH + ch] = v;
            }
        } else {
            unsigned pk[8];
            #pragma unroll
            for (int mt = 0; mt < 4; ++mt)
                #pragma unroll
                for (int rp = 0; rp < 2; ++rp) {
                    unsigned short sv[2];
                    #pragma unroll
                    for (int q2 = 0; q2 < 2; ++q2) {
                        int r = 2 * rp + q2;
                        float u = x0s * acc[mt][0][r] + x1s * acc[mt][1][r];
                        float sg = __builtin_amdgcn_rcpf(1.0f + exp2f(u));
                        sv[q2] = f2bf(sg);
                    }
                    pk[mt * 2 + rp] = (unsigned)sv[0] | ((unsigned)sv[1] << 16);
                }
            union { unsigned u[4]; bf16x8 v; } u0, u1;
            u0.u[0] = pk[0]; u0.u[1] = pk[1]; u0.u[2] = pk[2]; u0.u[3] = pk[3];
            u1.u[0] = pk[4]; u1.u[1] = pk[5]; u1.u[2] = pk[6]; u1.u[3] = pk[7];
            tf0 = u0.v; tf1 = u1.v;
        }
    }
}

extern "C" void kernel_launch(void* const* d_in, const int* in_sizes, int n_in,
                              void* d_out, int out_size, void* d_ws, size_t ws_size,
                              hipStream_t stream) {
    (void)in_sizes; (void)n_in; (void)out_size;
    const float* x    = (const float*)d_in[0];
    const float* tens = (const float*)d_in[1];
    float* out = (float*)d_out;
    if (ws_size >= WS_NEED) {
        short* wsA = (short*)d_ws;
        float* wsX = (float*)((char*)d_ws + WSA_SHORTS * 2);
        hipLaunchKernelGGL(prepass, dim3(NCH * LEN + 1024), dim3(1024), 0, stream,
                           x, tens, wsA, wsX);
        hipLaunchKernelGGL(mps_fwd15, dim3(640), dim3(128), 0, stream,
                           wsA, wsX, out);
    } else {
        hipLaunchKernelGGL(mps_fwd15_fb, dim3(640), dim3(64), 0, stream,
                           x, tens, out);
    }
}

// Round 16
// 513.726 us; speedup vs baseline: 1.0282x; 1.0282x over previous
//
#include <hip/hip_runtime.h>
#include <hip/hip_bf16.h>

// MPS chain: y[b,c] over 784 sites, chi=64, d=2, 10 ch, batch 1024.
// R16 = R13 VERBATIM (best: 514 us total, kernel ~455 us), restored after
// R15's m-split landed in the pre-registered "wash" branch (barrier+LDS
// round-trip ate the halved per-wave compute).
// Structure: barrier-free lane-local recurrence; one wave = 64x64 matrix x
// 16 batch cols; P-relabeled output bond (P(mt,mu)=32*(mt>>1)+8*(mu>>2)+
// 4*(mt&1)+(mu&3)) makes MFMA D == next-site B-frag lane-for-lane -> t-state
// never leaves VGPRs; bond-mask folded into wsA (prepass zeroes rows
// a>=dims[site]); inline-asm loads, 4 reg buffers, dist-2 prefetch, counted
// s_waitcnt vmcnt(16) + sched_barrier per body; setprio around MFMA; slim
// epilogue (builtin exp2 = raw v_exp_f32, paired RNE bf16 pack, hoisted Z).
// vmcnt ledger: prologue {2x,16 B0,16 B1} WAIT16 => x+B0 done, B1 in flight.
// body(n): issue 16 loads (site n+2); WAIT16 at end drains site n+1's
// prefetch => every body's reads drained one body earlier.
// Layouts (verified R1-R15): A-op m=l&15, k=8*(l>>4)+j; B-op col=l&15 same k;
// D row=4*(l>>4)+r, col=l&15.

#define LEN 784
#define NCH 10

typedef short bf16x8 __attribute__((ext_vector_type(8)));
typedef float f32x4  __attribute__((ext_vector_type(4)));
typedef unsigned int u32x4 __attribute__((ext_vector_type(4)));

#define WSA_SHORTS ((size_t)NCH * LEN * 8192)
#define WSX_FLOATS ((size_t)1024 * 2 * LEN)
#define WS_NEED (WSA_SHORTS * 2 + WSX_FLOATS * 4)

#define XSCALE -2.88539008177792681f   // -2*log2(e)
#define XUNDO  -0.34657359027997264f   // 1/XSCALE

static __device__ __forceinline__ unsigned short f2bf(float f) {
    union { __hip_bfloat16 h; unsigned short s; } u;
    u.h = __float2bfloat16(f);
    return u.s;
}

static __device__ __forceinline__ unsigned pack_bf2(float a, float b) {
    union { __hip_bfloat162 h; unsigned u; } c;
    c.h = __float22bfloat162_rn(float2{a, b});
    return c.u;
}

static __device__ __forceinline__ int site_dlim(int m) {
    int e1 = m < 6 ? (1 << m) : 64;
    int e2 = (LEN - m) < 6 ? (1 << (LEN - m)) : 64;
    return e1 < e2 ? e1 : e2;
}

// ---- pre-pass: tensors -> bf16 frag-order wsA (P-permuted m, masked rows),
//      x -> wsX[b][2n+i] pre-scaled by -2*log2(e) ----
__global__ __launch_bounds__(1024) void prepass(const float* __restrict__ x,
                                                const float* __restrict__ tens,
                                                short* __restrict__ wsA,
                                                float* __restrict__ wsX)
{
    const int bid = blockIdx.x;
    const int t = threadIdx.x;
    if (bid < NCH * LEN) {
        const int site = bid % LEN;
        const int dlim = site_dlim(site);
        const int mt = t >> 8, ii = (t >> 7) & 1, kf = (t >> 6) & 1, l = t & 63;
        const int l15 = l & 15;
        const int bout = 32 * (mt >> 1) + 8 * (l15 >> 2) + 4 * (mt & 1) + (l15 & 3);
        const int a0 = 32 * kf + 8 * (l >> 4);
        const float* src = tens + (size_t)bid * 8192;   // [a][i][bout]
        unsigned int wv[4];
        #pragma unroll
        for (int p = 0; p < 4; ++p) {
            int aA = a0 + 2 * p, aB = a0 + 2 * p + 1;
            float f0 = (aA < dlim) ? src[(size_t)aA * 128 + ii * 64 + bout] : 0.f;
            float f1 = (aB < dlim) ? src[(size_t)aB * 128 + ii * 64 + bout] : 0.f;
            wv[p] = (unsigned)f2bf(f0) | ((unsigned)f2bf(f1) << 16);
        }
        *(int4*)(wsA + (size_t)bid * 8192 + (size_t)t * 8) = *(int4*)wv;
    } else {
        int b = bid - NCH * LEN;
        if (t < LEN) {
            float v0 = x[(size_t)b * (2 * LEN) + t] * XSCALE;
            float v1 = x[(size_t)b * (2 * LEN) + LEN + t] * XSCALE;
            float2 pk; pk.x = v0; pk.y = v1;
            *(float2*)(wsX + (size_t)b * (2 * LEN) + 2 * t) = pk;
        }
    }
}

// one global_load_dwordx4: dst <- mem[sbase + voff + imm]
#define GLOAD(dst, voffr, sbase, imm) \
    asm volatile("global_load_dwordx4 %0, %1, %2 offset:" #imm \
                 : "=v"(dst) : "v"(voffr), "s"(sbase))

#define WAIT16() do { \
    asm volatile("s_waitcnt vmcnt(16)" ::: "memory"); \
    __builtin_amdgcn_sched_barrier(0); \
} while (0)

// ---- main chain kernel: one wave per block, barrier-free ----
__global__ __launch_bounds__(64) void mps_fwd16(const short* __restrict__ wsA,
                                                const float* __restrict__ wsX,
                                                float* __restrict__ out)
{
    const int lane = threadIdx.x;
    const int g = lane >> 4, l15 = lane & 15;

    // XCD-aware: 640 = 8 XCDs x 80 chains; each XCD sees <=2 channels
    const int p = blockIdx.x;
    const int gidx = (p & 7) * 80 + (p >> 3);
    const int ch = gidx >> 6;
    const int b0 = (gidx & 63) * 16;

    const short* asrc = wsA + (size_t)ch * LEN * 8192;
    const float* xsrc = wsX + (size_t)(b0 + l15) * (2 * LEN);

    const int voff0 = lane * 16;          // byte offsets for f-groups
    const int voff1 = voff0 + 4096;
    const int voff2 = voff0 + 8192;
    const int voff3 = voff0 + 12288;

    // hoisted zero-C operand (plain C++; materialized once)
    const f32x4 Z = (f32x4){0.f, 0.f, 0.f, 0.f};

    // t-state in registers: tf[kf][j] = t[32kf + 8g + j] for col l15
    bf16x8 tf0, tf1;
    #pragma unroll
    for (int j = 0; j < 8; ++j) { tf0[j] = 0; tf1[j] = 0; }
    if (g == 0) tf0[0] = (short)0x3F80;

    auto loadA = [&](int site, u32x4 (&A)[16]) {
        site = site < LEN ? site : LEN - 1;
        const short* sb = asrc + (size_t)site * 8192;
        GLOAD(A[0],  voff0, sb, 0);    GLOAD(A[1],  voff0, sb, 1024);
        GLOAD(A[2],  voff0, sb, 2048); GLOAD(A[3],  voff0, sb, 3072);
        GLOAD(A[4],  voff1, sb, 0);    GLOAD(A[5],  voff1, sb, 1024);
        GLOAD(A[6],  voff1, sb, 2048); GLOAD(A[7],  voff1, sb, 3072);
        GLOAD(A[8],  voff2, sb, 0);    GLOAD(A[9],  voff2, sb, 1024);
        GLOAD(A[10], voff2, sb, 2048); GLOAD(A[11], voff2, sb, 3072);
        GLOAD(A[12], voff3, sb, 0);    GLOAD(A[13], voff3, sb, 1024);
        GLOAD(A[14], voff3, sb, 2048); GLOAD(A[15], voff3, sb, 3072);
    };

    auto loadX = [&](int nb, float4& qa, float4& qb) {
        nb = nb <= LEN - 4 ? nb : LEN - 4;
        const float* sx = xsrc + 2 * nb;
        asm volatile("global_load_dwordx4 %0, %1, off"
                     : "=v"(qa) : "v"(sx));
        asm volatile("global_load_dwordx4 %0, %1, off offset:16"
                     : "=v"(qb) : "v"(sx));
    };

    auto body = [&](int n, u32x4 (&Ac)[16], u32x4 (&Al)[16],
                    float x0s, float x1s) {
        // (1) issue distance-2 prefetch (site n+2)
        loadA(n + 2, Al);
        __builtin_amdgcn_sched_barrier(0);

        // (2) 16 MFMA on current buffer; first kf consumes hoisted Z
        f32x4 acc[4][2];    // [mt][ii]
        __builtin_amdgcn_s_setprio(1);
        #pragma unroll
        for (int mt = 0; mt < 4; ++mt)
            #pragma unroll
            for (int ii = 0; ii < 2; ++ii) {
                f32x4 a0 = __builtin_amdgcn_mfma_f32_16x16x32_bf16(
                    __builtin_bit_cast(bf16x8, Ac[mt * 4 + ii * 2 + 0]),
                    tf0, Z, 0, 0, 0);
                acc[mt][ii] = __builtin_amdgcn_mfma_f32_16x16x32_bf16(
                    __builtin_bit_cast(bf16x8, Ac[mt * 4 + ii * 2 + 1]),
                    tf1, a0, 0, 0, 0);
            }
        __builtin_amdgcn_s_setprio(0);

        // (3) epilogue: x-combine + sigmoid -> next t frags (mask is in wsA)
        if (n == LEN - 1) {
            if (g == 0) {
                float v = (x0s * acc[0][0][0] + x1s * acc[0][1][0]) * XUNDO;
                out[(size_t)(b0 + l15) * NCH + ch] = v;
            }
        } else {
            unsigned pk[8];   // [mt][rpair]
            #pragma unroll
            for (int mt = 0; mt < 4; ++mt) {
                float s[4];
                #pragma unroll
                for (int r = 0; r < 4; ++r) {
                    float u = x0s * acc[mt][0][r] + x1s * acc[mt][1][r];
                    float ex = __builtin_amdgcn_exp2f(u);   // raw v_exp_f32
                    s[r] = __builtin_amdgcn_rcpf(1.0f + ex);
                }
                pk[mt * 2 + 0] = pack_bf2(s[0], s[1]);
                pk[mt * 2 + 1] = pack_bf2(s[2], s[3]);
            }
            union { unsigned u[4]; bf16x8 v; } u0, u1;
            u0.u[0] = pk[0]; u0.u[1] = pk[1]; u0.u[2] = pk[2]; u0.u[3] = pk[3];
            u1.u[0] = pk[4]; u1.u[1] = pk[5]; u1.u[2] = pk[6]; u1.u[3] = pk[7];
            tf0 = u0.v; tf1 = u1.v;
        }

        // (4) counted wait: the buffer for the NEXT body is now ready
        WAIT16();
    };

    u32x4 B0[16], B1[16], B2[16], B3[16];
    float4 xa, xb, xna, xnb;

    loadX(0, xa, xb);       // 2 loads
    loadA(0, B0);           // 16
    loadA(1, B1);           // 16  -> outstanding 34
    WAIT16();               // x + B0 ready; B1 in flight

    for (int nb = 0; nb < LEN; nb += 4) {
        loadX(nb + 4, xna, xnb);                  // drained in body0's WAIT16
        body(nb + 0, B0, B2, xa.x, xa.y);
        body(nb + 1, B1, B3, xa.z, xa.w);
        body(nb + 2, B2, B0, xb.x, xb.y);
        body(nb + 3, B3, B1, xb.z, xb.w);
        xa = xna; xb = xnb;
    }
}

// ---- fallback (ws too small): plain path on raw inputs ----
__global__ __launch_bounds__(64) void mps_fwd16_fb(const float* __restrict__ x,
                                                   const float* __restrict__ tens,
                                                   float* __restrict__ out)
{
    const int lane = threadIdx.x;
    const int g = lane >> 4, l15 = lane & 15;
    const int p = blockIdx.x;
    const int gidx = (p & 7) * 80 + (p >> 3);
    const int ch = gidx >> 6;
    const int b0 = (gidx & 63) * 16;

    const float* tsrc = tens + (size_t)ch * LEN * 8192;
    const float* xsrc = x + (size_t)(b0 + l15) * (2 * LEN);

    bf16x8 tf0, tf1;
    #pragma unroll
    for (int j = 0; j < 8; ++j) { tf0[j] = 0; tf1[j] = 0; }
    if (g == 0) tf0[0] = (short)0x3F80;

    for (int n = 0; n < LEN; ++n) {
        const int dlim = site_dlim(n);
        const float* sb = tsrc + (size_t)n * 8192;
        bf16x8 A[16];
        #pragma unroll
        for (int f = 0; f < 16; ++f) {
            int mt = f >> 2, ii = (f >> 1) & 1, kf = f & 1;
            int bout = 32 * (mt >> 1) + 8 * (l15 >> 2) + 4 * (mt & 1) + (l15 & 3);
            int a0 = 32 * kf + 8 * g;
            unsigned int wv[4];
            #pragma unroll
            for (int q2 = 0; q2 < 4; ++q2) {
                int aA = a0 + 2 * q2, aB = aA + 1;
                float f0 = (aA < dlim) ? sb[(size_t)aA * 128 + ii * 64 + bout] : 0.f;
                float f1 = (aB < dlim) ? sb[(size_t)aB * 128 + ii * 64 + bout] : 0.f;
                wv[q2] = (unsigned)f2bf(f0) | ((unsigned)f2bf(f1) << 16);
            }
            A[f] = *(bf16x8*)wv;
        }
        float x0s = xsrc[n] * XSCALE, x1s = xsrc[LEN + n] * XSCALE;

        f32x4 acc[4][2];
        #pragma unroll
        for (int mt = 0; mt < 4; ++mt)
            #pragma unroll
            for (int ii = 0; ii < 2; ++ii)
                acc[mt][ii] = (f32x4){0.f, 0.f, 0.f, 0.f};
        #pragma unroll
        for (int kf = 0; kf < 2; ++kf) {
            bf16x8 tfk = kf ? tf1 : tf0;
            #pragma unroll
            for (int mt = 0; mt < 4; ++mt)
                #pragma unroll
                for (int ii = 0; ii < 2; ++ii)
                    acc[mt][ii] = __builtin_amdgcn_mfma_f32_16x16x32_bf16(
                        A[mt * 4 + ii * 2 + kf], tfk, acc[mt][ii], 0, 0, 0);
        }

        if (n == LEN - 1) {
            if (g == 0) {
                float v = (x0s * acc[0][0][0] + x1s * acc[0][1][0]) * XUNDO;
                out[(size_t)(b0 + l15) * NCH + ch] = v;
            }
        } else {
            unsigned pk[8];
            #pragma unroll
            for (int mt = 0; mt < 4; ++mt)
                #pragma unroll
                for (int rp = 0; rp < 2; ++rp) {
                    unsigned short sv[2];
                    #pragma unroll
                    for (int q2 = 0; q2 < 2; ++q2) {
                        int r = 2 * rp + q2;
                        float u = x0s * acc[mt][0][r] + x1s * acc[mt][1][r];
                        float sg = __builtin_amdgcn_rcpf(1.0f + exp2f(u));
                        sv[q2] = f2bf(sg);
                    }
                    pk[mt * 2 + rp] = (unsigned)sv[0] | ((unsigned)sv[1] << 16);
                }
            union { unsigned u[4]; bf16x8 v; } u0, u1;
            u0.u[0] = pk[0]; u0.u[1] = pk[1]; u0.u[2] = pk[2]; u0.u[3] = pk[3];
            u1.u[0] = pk[4]; u1.u[1] = pk[5]; u1.u[2] = pk[6]; u1.u[3] = pk[7];
            tf0 = u0.v; tf1 = u1.v;
        }
    }
}

extern "C" void kernel_launch(void* const* d_in, const int* in_sizes, int n_in,
                              void* d_out, int out_size, void* d_ws, size_t ws_size,
                              hipStream_t stream) {
    (void)in_sizes; (void)n_in; (void)out_size;
    const float* x    = (const float*)d_in[0];
    const float* tens = (const float*)d_in[1];
    float* out = (float*)d_out;
    if (ws_size >= WS_NEED) {
        short* wsA = (short*)d_ws;
        float* wsX = (float*)((char*)d_ws + WSA_SHORTS * 2);
        hipLaunchKernelGGL(prepass, dim3(NCH * LEN + 1024), dim3(1024), 0, stream,
                           x, tens, wsA, wsX);
        hipLaunchKernelGGL(mps_fwd16, dim3(640), dim3(64), 0, stream,
                           wsA, wsX, out);
    } else {
        hipLaunchKernelGGL(mps_fwd16_fb, dim3(640), dim3(64), 0, stream,
                           x, tens, out);
    }
}

// Round 18
// 513.423 us; speedup vs baseline: 1.0289x; 1.0006x over previous
//
#include <hip/hip_runtime.h>
#include <hip/hip_bf16.h>

// MPS chain: y[b,c] over 784 sites, chi=64, d=2, 10 ch, batch 1024.
// R18 = R16 = R13 VERBATIM (best verified: 514 us total, kernel ~455 us,
// reproduced twice). R17's dist-3 probe was register-infeasible (8 asm-pinned
// buffers = 512 VGPRs -> runtime abort); dist-2 cover (~2800 cyc) already
// exceeds worst-case L3 latency, so the latency-tail theory is exhausted.
// Structure: barrier-free lane-local recurrence; one wave = 64x64 matrix x
// 16 batch cols; P-relabeled output bond (P(mt,mu)=32*(mt>>1)+8*(mu>>2)+
// 4*(mt&1)+(mu&3)) makes MFMA D == next-site B-frag lane-for-lane -> t-state
// never leaves VGPRs; bond-mask folded into wsA (prepass zeroes rows
// a>=dims[site]); inline-asm loads, 4 reg buffers, dist-2 prefetch, counted
// s_waitcnt vmcnt(16) + sched_barrier per body; setprio around MFMA; slim
// epilogue (builtin exp2 = raw v_exp_f32, paired RNE bf16 pack, hoisted Z).
// vmcnt ledger: prologue {2x,16 B0,16 B1} WAIT16 => x+B0 done, B1 in flight.
// body(n): issue 16 loads (site n+2); WAIT16 at end drains site n+1's
// prefetch => every body's reads drained one body earlier.
// Layouts (verified R1-R16): A-op m=l&15, k=8*(l>>4)+j; B-op col=l&15 same k;
// D row=4*(l>>4)+r, col=l&15.

#define LEN 784
#define NCH 10

typedef short bf16x8 __attribute__((ext_vector_type(8)));
typedef float f32x4  __attribute__((ext_vector_type(4)));
typedef unsigned int u32x4 __attribute__((ext_vector_type(4)));

#define WSA_SHORTS ((size_t)NCH * LEN * 8192)
#define WSX_FLOATS ((size_t)1024 * 2 * LEN)
#define WS_NEED (WSA_SHORTS * 2 + WSX_FLOATS * 4)

#define XSCALE -2.88539008177792681f   // -2*log2(e)
#define XUNDO  -0.34657359027997264f   // 1/XSCALE

static __device__ __forceinline__ unsigned short f2bf(float f) {
    union { __hip_bfloat16 h; unsigned short s; } u;
    u.h = __float2bfloat16(f);
    return u.s;
}

static __device__ __forceinline__ unsigned pack_bf2(float a, float b) {
    union { __hip_bfloat162 h; unsigned u; } c;
    c.h = __float22bfloat162_rn(float2{a, b});
    return c.u;
}

static __device__ __forceinline__ int site_dlim(int m) {
    int e1 = m < 6 ? (1 << m) : 64;
    int e2 = (LEN - m) < 6 ? (1 << (LEN - m)) : 64;
    return e1 < e2 ? e1 : e2;
}

// ---- pre-pass: tensors -> bf16 frag-order wsA (P-permuted m, masked rows),
//      x -> wsX[b][2n+i] pre-scaled by -2*log2(e) ----
__global__ __launch_bounds__(1024) void prepass(const float* __restrict__ x,
                                                const float* __restrict__ tens,
                                                short* __restrict__ wsA,
                                                float* __restrict__ wsX)
{
    const int bid = blockIdx.x;
    const int t = threadIdx.x;
    if (bid < NCH * LEN) {
        const int site = bid % LEN;
        const int dlim = site_dlim(site);
        const int mt = t >> 8, ii = (t >> 7) & 1, kf = (t >> 6) & 1, l = t & 63;
        const int l15 = l & 15;
        const int bout = 32 * (mt >> 1) + 8 * (l15 >> 2) + 4 * (mt & 1) + (l15 & 3);
        const int a0 = 32 * kf + 8 * (l >> 4);
        const float* src = tens + (size_t)bid * 8192;   // [a][i][bout]
        unsigned int wv[4];
        #pragma unroll
        for (int p = 0; p < 4; ++p) {
            int aA = a0 + 2 * p, aB = a0 + 2 * p + 1;
            float f0 = (aA < dlim) ? src[(size_t)aA * 128 + ii * 64 + bout] : 0.f;
            float f1 = (aB < dlim) ? src[(size_t)aB * 128 + ii * 64 + bout] : 0.f;
            wv[p] = (unsigned)f2bf(f0) | ((unsigned)f2bf(f1) << 16);
        }
        *(int4*)(wsA + (size_t)bid * 8192 + (size_t)t * 8) = *(int4*)wv;
    } else {
        int b = bid - NCH * LEN;
        if (t < LEN) {
            float v0 = x[(size_t)b * (2 * LEN) + t] * XSCALE;
            float v1 = x[(size_t)b * (2 * LEN) + LEN + t] * XSCALE;
            float2 pk; pk.x = v0; pk.y = v1;
            *(float2*)(wsX + (size_t)b * (2 * LEN) + 2 * t) = pk;
        }
    }
}

// one global_load_dwordx4: dst <- mem[sbase + voff + imm]
#define GLOAD(dst, voffr, sbase, imm) \
    asm volatile("global_load_dwordx4 %0, %1, %2 offset:" #imm \
                 : "=v"(dst) : "v"(voffr), "s"(sbase))

#define WAIT16() do { \
    asm volatile("s_waitcnt vmcnt(16)" ::: "memory"); \
    __builtin_amdgcn_sched_barrier(0); \
} while (0)

// ---- main chain kernel: one wave per block, barrier-free ----
__global__ __launch_bounds__(64) void mps_fwd18(const short* __restrict__ wsA,
                                                const float* __restrict__ wsX,
                                                float* __restrict__ out)
{
    const int lane = threadIdx.x;
    const int g = lane >> 4, l15 = lane & 15;

    // XCD-aware: 640 = 8 XCDs x 80 chains; each XCD sees <=2 channels
    const int p = blockIdx.x;
    const int gidx = (p & 7) * 80 + (p >> 3);
    const int ch = gidx >> 6;
    const int b0 = (gidx & 63) * 16;

    const short* asrc = wsA + (size_t)ch * LEN * 8192;
    const float* xsrc = wsX + (size_t)(b0 + l15) * (2 * LEN);

    const int voff0 = lane * 16;          // byte offsets for f-groups
    const int voff1 = voff0 + 4096;
    const int voff2 = voff0 + 8192;
    const int voff3 = voff0 + 12288;

    // hoisted zero-C operand (plain C++; materialized once)
    const f32x4 Z = (f32x4){0.f, 0.f, 0.f, 0.f};

    // t-state in registers: tf[kf][j] = t[32kf + 8g + j] for col l15
    bf16x8 tf0, tf1;
    #pragma unroll
    for (int j = 0; j < 8; ++j) { tf0[j] = 0; tf1[j] = 0; }
    if (g == 0) tf0[0] = (short)0x3F80;

    auto loadA = [&](int site, u32x4 (&A)[16]) {
        site = site < LEN ? site : LEN - 1;
        const short* sb = asrc + (size_t)site * 8192;
        GLOAD(A[0],  voff0, sb, 0);    GLOAD(A[1],  voff0, sb, 1024);
        GLOAD(A[2],  voff0, sb, 2048); GLOAD(A[3],  voff0, sb, 3072);
        GLOAD(A[4],  voff1, sb, 0);    GLOAD(A[5],  voff1, sb, 1024);
        GLOAD(A[6],  voff1, sb, 2048); GLOAD(A[7],  voff1, sb, 3072);
        GLOAD(A[8],  voff2, sb, 0);    GLOAD(A[9],  voff2, sb, 1024);
        GLOAD(A[10], voff2, sb, 2048); GLOAD(A[11], voff2, sb, 3072);
        GLOAD(A[12], voff3, sb, 0);    GLOAD(A[13], voff3, sb, 1024);
        GLOAD(A[14], voff3, sb, 2048); GLOAD(A[15], voff3, sb, 3072);
    };

    auto loadX = [&](int nb, float4& qa, float4& qb) {
        nb = nb <= LEN - 4 ? nb : LEN - 4;
        const float* sx = xsrc + 2 * nb;
        asm volatile("global_load_dwordx4 %0, %1, off"
                     : "=v"(qa) : "v"(sx));
        asm volatile("global_load_dwordx4 %0, %1, off offset:16"
                     : "=v"(qb) : "v"(sx));
    };

    auto body = [&](int n, u32x4 (&Ac)[16], u32x4 (&Al)[16],
                    float x0s, float x1s) {
        // (1) issue distance-2 prefetch (site n+2)
        loadA(n + 2, Al);
        __builtin_amdgcn_sched_barrier(0);

        // (2) 16 MFMA on current buffer; first kf consumes hoisted Z
        f32x4 acc[4][2];    // [mt][ii]
        __builtin_amdgcn_s_setprio(1);
        #pragma unroll
        for (int mt = 0; mt < 4; ++mt)
            #pragma unroll
            for (int ii = 0; ii < 2; ++ii) {
                f32x4 a0 = __builtin_amdgcn_mfma_f32_16x16x32_bf16(
                    __builtin_bit_cast(bf16x8, Ac[mt * 4 + ii * 2 + 0]),
                    tf0, Z, 0, 0, 0);
                acc[mt][ii] = __builtin_amdgcn_mfma_f32_16x16x32_bf16(
                    __builtin_bit_cast(bf16x8, Ac[mt * 4 + ii * 2 + 1]),
                    tf1, a0, 0, 0, 0);
            }
        __builtin_amdgcn_s_setprio(0);

        // (3) epilogue: x-combine + sigmoid -> next t frags (mask is in wsA)
        if (n == LEN - 1) {
            if (g == 0) {
                float v = (x0s * acc[0][0][0] + x1s * acc[0][1][0]) * XUNDO;
                out[(size_t)(b0 + l15) * NCH + ch] = v;
            }
        } else {
            unsigned pk[8];   // [mt][rpair]
            #pragma unroll
            for (int mt = 0; mt < 4; ++mt) {
                float s[4];
                #pragma unroll
                for (int r = 0; r < 4; ++r) {
                    float u = x0s * acc[mt][0][r] + x1s * acc[mt][1][r];
                    float ex = __builtin_amdgcn_exp2f(u);   // raw v_exp_f32
                    s[r] = __builtin_amdgcn_rcpf(1.0f + ex);
                }
                pk[mt * 2 + 0] = pack_bf2(s[0], s[1]);
                pk[mt * 2 + 1] = pack_bf2(s[2], s[3]);
            }
            union { unsigned u[4]; bf16x8 v; } u0, u1;
            u0.u[0] = pk[0]; u0.u[1] = pk[1]; u0.u[2] = pk[2]; u0.u[3] = pk[3];
            u1.u[0] = pk[4]; u1.u[1] = pk[5]; u1.u[2] = pk[6]; u1.u[3] = pk[7];
            tf0 = u0.v; tf1 = u1.v;
        }

        // (4) counted wait: the buffer for the NEXT body is now ready
        WAIT16();
    };

    u32x4 B0[16], B1[16], B2[16], B3[16];
    float4 xa, xb, xna, xnb;

    loadX(0, xa, xb);       // 2 loads
    loadA(0, B0);           // 16
    loadA(1, B1);           // 16  -> outstanding 34
    WAIT16();               // x + B0 ready; B1 in flight

    for (int nb = 0; nb < LEN; nb += 4) {
        loadX(nb + 4, xna, xnb);                  // drained in body0's WAIT16
        body(nb + 0, B0, B2, xa.x, xa.y);
        body(nb + 1, B1, B3, xa.z, xa.w);
        body(nb + 2, B2, B0, xb.x, xb.y);
        body(nb + 3, B3, B1, xb.z, xb.w);
        xa = xna; xb = xnb;
    }
}

// ---- fallback (ws too small): plain path on raw inputs ----
__global__ __launch_bounds__(64) void mps_fwd18_fb(const float* __restrict__ x,
                                                   const float* __restrict__ tens,
                                                   float* __restrict__ out)
{
    const int lane = threadIdx.x;
    const int g = lane >> 4, l15 = lane & 15;
    const int p = blockIdx.x;
    const int gidx = (p & 7) * 80 + (p >> 3);
    const int ch = gidx >> 6;
    const int b0 = (gidx & 63) * 16;

    const float* tsrc = tens + (size_t)ch * LEN * 8192;
    const float* xsrc = x + (size_t)(b0 + l15) * (2 * LEN);

    bf16x8 tf0, tf1;
    #pragma unroll
    for (int j = 0; j < 8; ++j) { tf0[j] = 0; tf1[j] = 0; }
    if (g == 0) tf0[0] = (short)0x3F80;

    for (int n = 0; n < LEN; ++n) {
        const int dlim = site_dlim(n);
        const float* sb = tsrc + (size_t)n * 8192;
        bf16x8 A[16];
        #pragma unroll
        for (int f = 0; f < 16; ++f) {
            int mt = f >> 2, ii = (f >> 1) & 1, kf = f & 1;
            int bout = 32 * (mt >> 1) + 8 * (l15 >> 2) + 4 * (mt & 1) + (l15 & 3);
            int a0 = 32 * kf + 8 * g;
            unsigned int wv[4];
            #pragma unroll
            for (int q2 = 0; q2 < 4; ++q2) {
                int aA = a0 + 2 * q2, aB = aA + 1;
                float f0 = (aA < dlim) ? sb[(size_t)aA * 128 + ii * 64 + bout] : 0.f;
                float f1 = (aB < dlim) ? sb[(size_t)aB * 128 + ii * 64 + bout] : 0.f;
                wv[q2] = (unsigned)f2bf(f0) | ((unsigned)f2bf(f1) << 16);
            }
            A[f] = *(bf16x8*)wv;
        }
        float x0s = xsrc[n] * XSCALE, x1s = xsrc[LEN + n] * XSCALE;

        f32x4 acc[4][2];
        #pragma unroll
        for (int mt = 0; mt < 4; ++mt)
            #pragma unroll
            for (int ii = 0; ii < 2; ++ii)
                acc[mt][ii] = (f32x4){0.f, 0.f, 0.f, 0.f};
        #pragma unroll
        for (int kf = 0; kf < 2; ++kf) {
            bf16x8 tfk = kf ? tf1 : tf0;
            #pragma unroll
            for (int mt = 0; mt < 4; ++mt)
                #pragma unroll
                for (int ii = 0; ii < 2; ++ii)
                    acc[mt][ii] = __builtin_amdgcn_mfma_f32_16x16x32_bf16(
                        A[mt * 4 + ii * 2 + kf], tfk, acc[mt][ii], 0, 0, 0);
        }

        if (n == LEN - 1) {
            if (g == 0) {
                float v = (x0s * acc[0][0][0] + x1s * acc[0][1][0]) * XUNDO;
                out[(size_t)(b0 + l15) * NCH + ch] = v;
            }
        } else {
            unsigned pk[8];
            #pragma unroll
            for (int mt = 0; mt < 4; ++mt)
                #pragma unroll
                for (int rp = 0; rp < 2; ++rp) {
                    unsigned short sv[2];
                    #pragma unroll
                    for (int q2 = 0; q2 < 2; ++q2) {
                        int r = 2 * rp + q2;
                        float u = x0s * acc[mt][0][r] + x1s * acc[mt][1][r];
                        float sg = __builtin_amdgcn_rcpf(1.0f + exp2f(u));
                        sv[q2] = f2bf(sg);
                    }
                    pk[mt * 2 + rp] = (unsigned)sv[0] | ((unsigned)sv[1] << 16);
                }
            union { unsigned u[4]; bf16x8 v; } u0, u1;
            u0.u[0] = pk[0]; u0.u[1] = pk[1]; u0.u[2] = pk[2]; u0.u[3] = pk[3];
            u1.u[0] = pk[4]; u1.u[1] = pk[5]; u1.u[2] = pk[6]; u1.u[3] = pk[7];
            tf0 = u0.v; tf1 = u1.v;
        }
    }
}

extern "C" void kernel_launch(void* const* d_in, const int* in_sizes, int n_in,
                              void* d_out, int out_size, void* d_ws, size_t ws_size,
                              hipStream_t stream) {
    (void)in_sizes; (void)n_in; (void)out_size;
    const float* x    = (const float*)d_in[0];
    const float* tens = (const float*)d_in[1];
    float* out = (float*)d_out;
    if (ws_size >= WS_NEED) {
        short* wsA = (short*)d_ws;
        float* wsX = (float*)((char*)d_ws + WSA_SHORTS * 2);
        hipLaunchKernelGGL(prepass, dim3(NCH * LEN + 1024), dim3(1024), 0, stream,
                           x, tens, wsA, wsX);
        hipLaunchKernelGGL(mps_fwd18, dim3(640), dim3(64), 0, stream,
                           wsA, wsX, out);
    } else {
        hipLaunchKernelGGL(mps_fwd18_fb, dim3(640), dim3(64), 0, stream,
                           x, tens, out);
    }
}

// Round 19
// 511.717 us; speedup vs baseline: 1.0323x; 1.0033x over previous
//
#include <hip/hip_runtime.h>
#include <hip/hip_bf16.h>

// MPS chain: y[b,c] over 784 sites, chi=64, d=2, 10 ch, batch 1024.
// R18 = R16 = R13 VERBATIM (best verified: 514 us total, kernel ~455 us,
// reproduced twice). R17's dist-3 probe was register-infeasible (8 asm-pinned
// buffers = 512 VGPRs -> runtime abort); dist-2 cover (~2800 cyc) already
// exceeds worst-case L3 latency, so the latency-tail theory is exhausted.
// Structure: barrier-free lane-local recurrence; one wave = 64x64 matrix x
// 16 batch cols; P-relabeled output bond (P(mt,mu)=32*(mt>>1)+8*(mu>>2)+
// 4*(mt&1)+(mu&3)) makes MFMA D == next-site B-frag lane-for-lane -> t-state
// never leaves VGPRs; bond-mask folded into wsA (prepass zeroes rows
// a>=dims[site]); inline-asm loads, 4 reg buffers, dist-2 prefetch, counted
// s_waitcnt vmcnt(16) + sched_barrier per body; setprio around MFMA; slim
// epilogue (builtin exp2 = raw v_exp_f32, paired RNE bf16 pack, hoisted Z).
// vmcnt ledger: prologue {2x,16 B0,16 B1} WAIT16 => x+B0 done, B1 in flight.
// body(n): issue 16 loads (site n+2); WAIT16 at end drains site n+1's
// prefetch => every body's reads drained one body earlier.
// Layouts (verified R1-R16): A-op m=l&15, k=8*(l>>4)+j; B-op col=l&15 same k;
// D row=4*(l>>4)+r, col=l&15.

#define LEN 784
#define NCH 10

typedef short bf16x8 __attribute__((ext_vector_type(8)));
typedef float f32x4  __attribute__((ext_vector_type(4)));
typedef unsigned int u32x4 __attribute__((ext_vector_type(4)));

#define WSA_SHORTS ((size_t)NCH * LEN * 8192)
#define WSX_FLOATS ((size_t)1024 * 2 * LEN)
#define WS_NEED (WSA_SHORTS * 2 + WSX_FLOATS * 4)

#define XSCALE -2.88539008177792681f   // -2*log2(e)
#define XUNDO  -0.34657359027997264f   // 1/XSCALE

static __device__ __forceinline__ unsigned short f2bf(float f) {
    union { __hip_bfloat16 h; unsigned short s; } u;
    u.h = __float2bfloat16(f);
    return u.s;
}

static __device__ __forceinline__ unsigned pack_bf2(float a, float b) {
    union { __hip_bfloat162 h; unsigned u; } c;
    c.h = __float22bfloat162_rn(float2{a, b});
    return c.u;
}

static __device__ __forceinline__ int site_dlim(int m) {
    int e1 = m < 6 ? (1 << m) : 64;
    int e2 = (LEN - m) < 6 ? (1 << (LEN - m)) : 64;
    return e1 < e2 ? e1 : e2;
}

// ---- pre-pass: tensors -> bf16 frag-order wsA (P-permuted m, masked rows),
//      x -> wsX[b][2n+i] pre-scaled by -2*log2(e) ----
__global__ __launch_bounds__(1024) void prepass(const float* __restrict__ x,
                                                const float* __restrict__ tens,
                                                short* __restrict__ wsA,
                                                float* __restrict__ wsX)
{
    const int bid = blockIdx.x;
    const int t = threadIdx.x;
    if (bid < NCH * LEN) {
        const int site = bid % LEN;
        const int dlim = site_dlim(site);
        const int mt = t >> 8, ii = (t >> 7) & 1, kf = (t >> 6) & 1, l = t & 63;
        const int l15 = l & 15;
        const int bout = 32 * (mt >> 1) + 8 * (l15 >> 2) + 4 * (mt & 1) + (l15 & 3);
        const int a0 = 32 * kf + 8 * (l >> 4);
        const float* src = tens + (size_t)bid * 8192;   // [a][i][bout]
        unsigned int wv[4];
        #pragma unroll
        for (int p = 0; p < 4; ++p) {
            int aA = a0 + 2 * p, aB = a0 + 2 * p + 1;
            float f0 = (aA < dlim) ? src[(size_t)aA * 128 + ii * 64 + bout] : 0.f;
            float f1 = (aB < dlim) ? src[(size_t)aB * 128 + ii * 64 + bout] : 0.f;
            wv[p] = (unsigned)f2bf(f0) | ((unsigned)f2bf(f1) << 16);
        }
        *(int4*)(wsA + (size_t)bid * 8192 + (size_t)t * 8) = *(int4*)wv;
    } else {
        int b = bid - NCH * LEN;
        if (t < LEN) {
            float v0 = x[(size_t)b * (2 * LEN) + t] * XSCALE;
            float v1 = x[(size_t)b * (2 * LEN) + LEN + t] * XSCALE;
            float2 pk; pk.x = v0; pk.y = v1;
            *(float2*)(wsX + (size_t)b * (2 * LEN) + 2 * t) = pk;
        }
    }
}

// one global_load_dwordx4: dst <- mem[sbase + voff + imm]
#define GLOAD(dst, voffr, sbase, imm) \
    asm volatile("global_load_dwordx4 %0, %1, %2 offset:" #imm \
                 : "=v"(dst) : "v"(voffr), "s"(sbase))

#define WAIT16() do { \
    asm volatile("s_waitcnt vmcnt(16)" ::: "memory"); \
    __builtin_amdgcn_sched_barrier(0); \
} while (0)

// ---- main chain kernel: one wave per block, barrier-free ----
__global__ __launch_bounds__(64) void mps_fwd18(const short* __restrict__ wsA,
                                                const float* __restrict__ wsX,
                                                float* __restrict__ out)
{
    const int lane = threadIdx.x;
    const int g = lane >> 4, l15 = lane & 15;

    // XCD-aware: 640 = 8 XCDs x 80 chains; each XCD sees <=2 channels
    const int p = blockIdx.x;
    const int gidx = (p & 7) * 80 + (p >> 3);
    const int ch = gidx >> 6;
    const int b0 = (gidx & 63) * 16;

    const short* asrc = wsA + (size_t)ch * LEN * 8192;
    const float* xsrc = wsX + (size_t)(b0 + l15) * (2 * LEN);

    const int voff0 = lane * 16;          // byte offsets for f-groups
    const int voff1 = voff0 + 4096;
    const int voff2 = voff0 + 8192;
    const int voff3 = voff0 + 12288;

    // hoisted zero-C operand (plain C++; materialized once)
    const f32x4 Z = (f32x4){0.f, 0.f, 0.f, 0.f};

    // t-state in registers: tf[kf][j] = t[32kf + 8g + j] for col l15
    bf16x8 tf0, tf1;
    #pragma unroll
    for (int j = 0; j < 8; ++j) { tf0[j] = 0; tf1[j] = 0; }
    if (g == 0) tf0[0] = (short)0x3F80;

    auto loadA = [&](int site, u32x4 (&A)[16]) {
        site = site < LEN ? site : LEN - 1;
        const short* sb = asrc + (size_t)site * 8192;
        GLOAD(A[0],  voff0, sb, 0);    GLOAD(A[1],  voff0, sb, 1024);
        GLOAD(A[2],  voff0, sb, 2048); GLOAD(A[3],  voff0, sb, 3072);
        GLOAD(A[4],  voff1, sb, 0);    GLOAD(A[5],  voff1, sb, 1024);
        GLOAD(A[6],  voff1, sb, 2048); GLOAD(A[7],  voff1, sb, 3072);
        GLOAD(A[8],  voff2, sb, 0);    GLOAD(A[9],  voff2, sb, 1024);
        GLOAD(A[10], voff2, sb, 2048); GLOAD(A[11], voff2, sb, 3072);
        GLOAD(A[12], voff3, sb, 0);    GLOAD(A[13], voff3, sb, 1024);
        GLOAD(A[14], voff3, sb, 2048); GLOAD(A[15], voff3, sb, 3072);
    };

    auto loadX = [&](int nb, float4& qa, float4& qb) {
        nb = nb <= LEN - 4 ? nb : LEN - 4;
        const float* sx = xsrc + 2 * nb;
        asm volatile("global_load_dwordx4 %0, %1, off"
                     : "=v"(qa) : "v"(sx));
        asm volatile("global_load_dwordx4 %0, %1, off offset:16"
                     : "=v"(qb) : "v"(sx));
    };

    auto body = [&](int n, u32x4 (&Ac)[16], u32x4 (&Al)[16],
                    float x0s, float x1s) {
        // (1) issue distance-2 prefetch (site n+2)
        loadA(n + 2, Al);
        __builtin_amdgcn_sched_barrier(0);

        // (2) 16 MFMA on current buffer; first kf consumes hoisted Z
        f32x4 acc[4][2];    // [mt][ii]
        __builtin_amdgcn_s_setprio(1);
        #pragma unroll
        for (int mt = 0; mt < 4; ++mt)
            #pragma unroll
            for (int ii = 0; ii < 2; ++ii) {
                f32x4 a0 = __builtin_amdgcn_mfma_f32_16x16x32_bf16(
                    __builtin_bit_cast(bf16x8, Ac[mt * 4 + ii * 2 + 0]),
                    tf0, Z, 0, 0, 0);
                acc[mt][ii] = __builtin_amdgcn_mfma_f32_16x16x32_bf16(
                    __builtin_bit_cast(bf16x8, Ac[mt * 4 + ii * 2 + 1]),
                    tf1, a0, 0, 0, 0);
            }
        __builtin_amdgcn_s_setprio(0);

        // (3) epilogue: x-combine + sigmoid -> next t frags (mask is in wsA)
        if (n == LEN - 1) {
            if (g == 0) {
                float v = (x0s * acc[0][0][0] + x1s * acc[0][1][0]) * XUNDO;
                out[(size_t)(b0 + l15) * NCH + ch] = v;
            }
        } else {
            unsigned pk[8];   // [mt][rpair]
            #pragma unroll
            for (int mt = 0; mt < 4; ++mt) {
                float s[4];
                #pragma unroll
                for (int r = 0; r < 4; ++r) {
                    float u = x0s * acc[mt][0][r] + x1s * acc[mt][1][r];
                    float ex = __builtin_amdgcn_exp2f(u);   // raw v_exp_f32
                    s[r] = __builtin_amdgcn_rcpf(1.0f + ex);
                }
                pk[mt * 2 + 0] = pack_bf2(s[0], s[1]);
                pk[mt * 2 + 1] = pack_bf2(s[2], s[3]);
            }
            union { unsigned u[4]; bf16x8 v; } u0, u1;
            u0.u[0] = pk[0]; u0.u[1] = pk[1]; u0.u[2] = pk[2]; u0.u[3] = pk[3];
            u1.u[0] = pk[4]; u1.u[1] = pk[5]; u1.u[2] = pk[6]; u1.u[3] = pk[7];
            tf0 = u0.v; tf1 = u1.v;
        }

        // (4) counted wait: the buffer for the NEXT body is now ready
        WAIT16();
    };

    u32x4 B0[16], B1[16], B2[16], B3[16];
    float4 xa, xb, xna, xnb;

    loadX(0, xa, xb);       // 2 loads
    loadA(0, B0);           // 16
    loadA(1, B1);           // 16  -> outstanding 34
    WAIT16();               // x + B0 ready; B1 in flight

    for (int nb = 0; nb < LEN; nb += 4) {
        loadX(nb + 4, xna, xnb);                  // drained in body0's WAIT16
        body(nb + 0, B0, B2, xa.x, xa.y);
        body(nb + 1, B1, B3, xa.z, xa.w);
        body(nb + 2, B2, B0, xb.x, xb.y);
        body(nb + 3, B3, B1, xb.z, xb.w);
        xa = xna; xb = xnb;
    }
}

// ---- fallback (ws too small): plain path on raw inputs ----
__global__ __launch_bounds__(64) void mps_fwd18_fb(const float* __restrict__ x,
                                                   const float* __restrict__ tens,
                                                   float* __restrict__ out)
{
    const int lane = threadIdx.x;
    const int g = lane >> 4, l15 = lane & 15;
    const int p = blockIdx.x;
    const int gidx = (p & 7) * 80 + (p >> 3);
    const int ch = gidx >> 6;
    const int b0 = (gidx & 63) * 16;

    const float* tsrc = tens + (size_t)ch * LEN * 8192;
    const float* xsrc = x + (size_t)(b0 + l15) * (2 * LEN);

    bf16x8 tf0, tf1;
    #pragma unroll
    for (int j = 0; j < 8; ++j) { tf0[j] = 0; tf1[j] = 0; }
    if (g == 0) tf0[0] = (short)0x3F80;

    for (int n = 0; n < LEN; ++n) {
        const int dlim = site_dlim(n);
        const float* sb = tsrc + (size_t)n * 8192;
        bf16x8 A[16];
        #pragma unroll
        for (int f = 0; f < 16; ++f) {
            int mt = f >> 2, ii = (f >> 1) & 1, kf = f & 1;
            int bout = 32 * (mt >> 1) + 8 * (l15 >> 2) + 4 * (mt & 1) + (l15 & 3);
            int a0 = 32 * kf + 8 * g;
            unsigned int wv[4];
            #pragma unroll
            for (int q2 = 0; q2 < 4; ++q2) {
                int aA = a0 + 2 * q2, aB = aA + 1;
                float f0 = (aA < dlim) ? sb[(size_t)aA * 128 + ii * 64 + bout] : 0.f;
                float f1 = (aB < dlim) ? sb[(size_t)aB * 128 + ii * 64 + bout] : 0.f;
                wv[q2] = (unsigned)f2bf(f0) | ((unsigned)f2bf(f1) << 16);
            }
            A[f] = *(bf16x8*)wv;
        }
        float x0s = xsrc[n] * XSCALE, x1s = xsrc[LEN + n] * XSCALE;

        f32x4 acc[4][2];
        #pragma unroll
        for (int mt = 0; mt < 4; ++mt)
            #pragma unroll
            for (int ii = 0; ii < 2; ++ii)
                acc[mt][ii] = (f32x4){0.f, 0.f, 0.f, 0.f};
        #pragma unroll
        for (int kf = 0; kf < 2; ++kf) {
            bf16x8 tfk = kf ? tf1 : tf0;
            #pragma unroll
            for (int mt = 0; mt < 4; ++mt)
                #pragma unroll
                for (int ii = 0; ii < 2; ++ii)
                    acc[mt][ii] = __builtin_amdgcn_mfma_f32_16x16x32_bf16(
                        A[mt * 4 + ii * 2 + kf], tfk, acc[mt][ii], 0, 0, 0);
        }

        if (n == LEN - 1) {
            if (g == 0) {
                float v = (x0s * acc[0][0][0] + x1s * acc[0][1][0]) * XUNDO;
                out[(size_t)(b0 + l15) * NCH + ch] = v;
            }
        } else {
            unsigned pk[8];
            #pragma unroll
            for (int mt = 0; mt < 4; ++mt)
                #pragma unroll
                for (int rp = 0; rp < 2; ++rp) {
                    unsigned short sv[2];
                    #pragma unroll
                    for (int q2 = 0; q2 < 2; ++q2) {
                        int r = 2 * rp + q2;
                        float u = x0s * acc[mt][0][r] + x1s * acc[mt][1][r];
                        float sg = __builtin_amdgcn_rcpf(1.0f + exp2f(u));
                        sv[q2] = f2bf(sg);
                    }
                    pk[mt * 2 + rp] = (unsigned)sv[0] | ((unsigned)sv[1] << 16);
                }
            union { unsigned u[4]; bf16x8 v; } u0, u1;
            u0.u[0] = pk[0]; u0.u[1] = pk[1]; u0.u[2] = pk[2]; u0.u[3] = pk[3];
            u1.u[0] = pk[4]; u1.u[1] = pk[5]; u1.u[2] = pk[6]; u1.u[3] = pk[7];
            tf0 = u0.v; tf1 = u1.v;
        }
    }
}

extern "C" void kernel_launch(void* const* d_in, const int* in_sizes, int n_in,
                              void* d_out, int out_size, void* d_ws, size_t ws_size,
                              hipStream_t stream) {
    (void)in_sizes; (void)n_in; (void)out_size;
    const float* x    = (const float*)d_in[0];
    const float* tens = (const float*)d_in[1];
    float* out = (float*)d_out;
    if (ws_size >= WS_NEED) {
        short* wsA = (short*)d_ws;
        float* wsX = (float*)((char*)d_ws + WSA_SHORTS * 2);
        hipLaunchKernelGGL(prepass, dim3(NCH * LEN + 1024), dim3(1024), 0, stream,
                           x, tens, wsA, wsX);
        hipLaunchKernelGGL(mps_fwd18, dim3(640), dim3(64), 0, stream,
                           wsA, wsX, out);
    } else {
        hipLaunchKernelGGL(mps_fwd18_fb, dim3(640), dim3(64), 0, stream,
                           x, tens, out);
    }
}